// Round 2
// baseline (2906.376 us; speedup 1.0000x reference)
//
#include <hip/hip_runtime.h>
#include <stdint.h>

#define NB    16   // batches
#define WPB   16   // workgroups per batch
#define NTHR  512  // threads per workgroup (8 waves)
#define NWAVE (NTHR / 64)
#define PPT   16   // points per thread = 131072 / (WPB*NTHR)

// JAX Threefry-2x32 (20 rounds), exact.
__device__ __forceinline__ void tf2x32(uint32_t k0, uint32_t k1,
                                       uint32_t x0, uint32_t x1,
                                       uint32_t &y0, uint32_t &y1) {
  uint32_t ks2 = k0 ^ k1 ^ 0x1BD11BDAu;
  uint32_t v0 = x0 + k0, v1 = x1 + k1;
#define TFR(r) { v0 += v1; v1 = (v1 << (r)) | (v1 >> (32 - (r))); v1 ^= v0; }
  TFR(13) TFR(15) TFR(26) TFR(6)   v0 += k1;  v1 += ks2 + 1u;
  TFR(17) TFR(29) TFR(16) TFR(24)  v0 += ks2; v1 += k0 + 2u;
  TFR(13) TFR(15) TFR(26) TFR(6)   v0 += k0;  v1 += k1 + 3u;
  TFR(17) TFR(29) TFR(16) TFR(24)  v0 += k1;  v1 += ks2 + 4u;
  TFR(13) TFR(15) TFR(26) TFR(6)   v0 += ks2; v1 += k0 + 5u;
#undef TFR
  y0 = v0; y1 = v1;
}

// Slot layout (u64 words), per (parity, batch): 16 slots x 4 words = 64 u64.
//  word0: [tag:13 | dist_bits:32 | inv_idx:19]   (reduce key)
//  word1: [x_bits:32 | tag:32]
//  word2: [y_bits:32 | tag:32]
//  word3: [z_bits:32 | tag:32]
// Every word carries the tag -> no release/acquire ordering needed; a
// consistent snapshot is "all 64 words show tag i+1".

__global__ __launch_bounds__(NTHR, 2)
void FPSampler_42099269435595_kernel(const float* __restrict__ xyz,
                                     const int* __restrict__ npoint_ptr,
                                     float* __restrict__ out,
                                     unsigned long long* __restrict__ slots,
                                     int N) {
  const int blk  = blockIdx.x;
  const int b    = blk >> 4;          // batch
  const int w    = blk & (WPB - 1);   // wg within batch
  const int tid  = threadIdx.x;
  const int wave = tid >> 6;
  const int lane = tid & 63;
  const int npoint = npoint_ptr[0];

  const float* __restrict__ xb = xyz + (size_t)b * N * 3;
  const int p0 = w * (N / WPB) + tid;

  // Load point slice; pin to VGPRs so the compiler cannot sink the loads
  // back into the iteration loop (R1: it did, VGPR=56, per-iter L2 re-reads).
  float px[PPT], py[PPT], pz[PPT], dist[PPT];
#pragma unroll
  for (int k = 0; k < PPT; ++k) {
    size_t p = (size_t)(p0 + k * NTHR);
    px[k] = xb[3 * p + 0];
    py[k] = xb[3 * p + 1];
    pz[k] = xb[3 * p + 2];
    dist[k] = 1e10f;
  }
#pragma unroll
  for (int k = 0; k < PPT; ++k) {
    asm volatile("" : "+v"(px[k]), "+v"(py[k]), "+v"(pz[k]));
  }

  // start = randint(fold_in(key(0),1),(16,),0,2^17)  (threefry, partitionable)
  uint32_t fk0, fk1, s0, s1, r0, r1;
  tf2x32(0u, 0u, 0u, 1u, fk0, fk1);          // fold_in(key(0), 1)
  tf2x32(fk0, fk1, 0u, 1u, s0, s1);          // split(key)[1]
  tf2x32(s0, s1, 0u, (uint32_t)b, r0, r1);   // random_bits element b
  uint32_t far = (r0 ^ r1) & 0x1FFFFu;       // % 131072 (span = 2^17)

  // initial centroid coords (uniform broadcast load, once)
  float cx = xb[3 * (size_t)far + 0];
  float cy = xb[3 * (size_t)far + 1];
  float cz = xb[3 * (size_t)far + 2];

  __shared__ unsigned long long lds_key[NWAVE];
  __shared__ float lds_x[NWAVE], lds_y[NWAVE], lds_z[NWAVE];
  __shared__ unsigned int lds_bfar;
  __shared__ float lds_bcx, lds_bcy, lds_bcz;

  float* out_xyz = out;                           // (B, npoint, 3)
  float* out_idx = out + (size_t)NB * npoint * 3; // (B, npoint) as float

  for (int i = 0; i < npoint; ++i) {
    if (w == 0 && tid == 0) {
      size_t o = (size_t)b * npoint + i;
      out_xyz[3 * o + 0] = cx;
      out_xyz[3 * o + 1] = cy;
      out_xyz[3 * o + 2] = cz;
      out_idx[o] = (float)far;     // scan emits farthest BEFORE update
    }
    if (i == npoint - 1) break;

    // ---- distance update + per-thread argmax (coords carried along) ----
    float best = -1.0f, bx = 0.f, by = 0.f, bz = 0.f;
    uint32_t bidx = 0;
#pragma unroll
    for (int k = 0; k < PPT; ++k) {
#pragma clang fp contract(off)
      float dx = px[k] - cx, dy = py[k] - cy, dz = pz[k] - cz;
      float d = (dx * dx + dy * dy) + dz * dz;  // match XLA: no FMA contraction
      float nd = fminf(dist[k], d);
      dist[k] = nd;
      if (nd > best) {
        best = nd; bidx = (uint32_t)(p0 + k * NTHR);
        bx = px[k]; by = py[k]; bz = pz[k];
      }
    }

    // ---- per-wave reduce: key only, then ballot+shfl the winner coords ----
    unsigned long long mykey =
        ((unsigned long long)__float_as_uint(best) << 19) |
        (unsigned long long)(0x7FFFFu - bidx);
    unsigned long long pk = mykey;
#pragma unroll
    for (int off = 32; off >= 1; off >>= 1) {
      unsigned long long o = __shfl_xor(pk, off);
      if (o > pk) pk = o;
    }
    unsigned long long bal = __ballot(mykey == pk);  // unique keys -> 1 bit
    int wl = __ffsll(bal) - 1;
    float wx = __shfl(bx, wl), wy = __shfl(by, wl), wz = __shfl(bz, wl);
    if (lane == 0) {
      lds_key[wave] = pk;
      lds_x[wave] = wx; lds_y[wave] = wy; lds_z[wave] = wz;
    }
    __syncthreads();

    unsigned long long* base =
        slots + (size_t)(((i & 1) * NB + b)) * (WPB * 4);
    const uint32_t tag = (uint32_t)(i + 1);

    if (wave == 0) {
      // cross-wave pick (lanes 0..7), then tid0 publishes 4 tagged words
      unsigned long long k8 = (lane < NWAVE) ? lds_key[lane] : 0ull;
      unsigned long long m8 = k8;
#pragma unroll
      for (int off = 4; off >= 1; off >>= 1) {
        unsigned long long o = __shfl_xor(m8, off);
        if (o > m8) m8 = o;
      }
      unsigned long long bal8 = __ballot(lane < NWAVE && k8 == m8);
      int wv = __ffsll(bal8) - 1;
      if (lane == 0) {
        unsigned long long* myslot = base + w * 4;
        unsigned long long word0 = ((unsigned long long)tag << 51) | m8;
        unsigned long long w1 =
            ((unsigned long long)__float_as_uint(lds_x[wv]) << 32) | tag;
        unsigned long long w2 =
            ((unsigned long long)__float_as_uint(lds_y[wv]) << 32) | tag;
        unsigned long long w3 =
            ((unsigned long long)__float_as_uint(lds_z[wv]) << 32) | tag;
        __hip_atomic_store(&myslot[0], word0, __ATOMIC_RELAXED,
                           __HIP_MEMORY_SCOPE_AGENT);
        __hip_atomic_store(&myslot[1], w1, __ATOMIC_RELAXED,
                           __HIP_MEMORY_SCOPE_AGENT);
        __hip_atomic_store(&myslot[2], w2, __ATOMIC_RELAXED,
                           __HIP_MEMORY_SCOPE_AGENT);
        __hip_atomic_store(&myslot[3], w3, __ATOMIC_RELAXED,
                           __HIP_MEMORY_SCOPE_AGENT);
      }

      // ---- poll: lane j holds word (j&3) of slot (j>>2); one load/lane ----
      unsigned long long v;
      uint32_t t;
      do {
        v = __hip_atomic_load(base + lane, __ATOMIC_RELAXED,
                              __HIP_MEMORY_SCOPE_AGENT);
        t = (lane & 3) ? (uint32_t)v : (uint32_t)(v >> 51);
      } while (__any(t != tag));

      // redistribute: every lane grabs slot (lane&15)'s key, 16-way max
      unsigned long long key = __shfl(v, (lane & 15) << 2);
      unsigned long long gk = key;
#pragma unroll
      for (int off = 8; off >= 1; off >>= 1) {
        unsigned long long o = __shfl_xor(gk, off);
        if (o > gk) gk = o;
      }
      unsigned long long gbal = __ballot(key == gk);
      int ws = (__ffsll(gbal) - 1) & 15;   // winner slot
      uint32_t nfar = 0x7FFFFu - (uint32_t)(gk & 0x7FFFFu);
      float ncx = __uint_as_float((uint32_t)(__shfl(v, (ws << 2) | 1) >> 32));
      float ncy = __uint_as_float((uint32_t)(__shfl(v, (ws << 2) | 2) >> 32));
      float ncz = __uint_as_float((uint32_t)(__shfl(v, (ws << 2) | 3) >> 32));
      if (lane == 0) {
        lds_bfar = nfar;
        lds_bcx = ncx; lds_bcy = ncy; lds_bcz = ncz;
      }
    }
    __syncthreads();
    far = lds_bfar;
    cx = lds_bcx; cy = lds_bcy; cz = lds_bcz;
  }
}

extern "C" void kernel_launch(void* const* d_in, const int* in_sizes, int n_in,
                              void* d_out, int out_size, void* d_ws, size_t ws_size,
                              hipStream_t stream) {
  const float* xyz = (const float*)d_in[0];
  const int* npoint = (const int*)d_in[1];
  int N = in_sizes[0] / (NB * 3);  // 131072

  // zero slot words (2 parities x NB x WPB x 4 u64 = 16 KiB); tag 0 never
  // matches (tags start at 1), 0xAA poison decodes to tag 5461 -> also safe.
  hipMemsetAsync(d_ws, 0,
                 (size_t)2 * NB * WPB * 4 * sizeof(unsigned long long),
                 stream);
  FPSampler_42099269435595_kernel<<<NB * WPB, NTHR, 0, stream>>>(
      xyz, npoint, (float*)d_out, (unsigned long long*)d_ws, N);
}

// Round 3
// 2857.967 us; speedup vs baseline: 1.0169x; 1.0169x over previous
//
#include <hip/hip_runtime.h>
#include <stdint.h>

#define NB    16   // batches
#define WPB   16   // workgroups per batch
#define NTHR  512  // threads per workgroup (8 waves)
#define NWAVE (NTHR / 64)
#define PPT   16   // points per thread = 131072 / (WPB*NTHR)

// JAX Threefry-2x32 (20 rounds), exact.
__device__ __forceinline__ void tf2x32(uint32_t k0, uint32_t k1,
                                       uint32_t x0, uint32_t x1,
                                       uint32_t &y0, uint32_t &y1) {
  uint32_t ks2 = k0 ^ k1 ^ 0x1BD11BDAu;
  uint32_t v0 = x0 + k0, v1 = x1 + k1;
#define TFR(r) { v0 += v1; v1 = (v1 << (r)) | (v1 >> (32 - (r))); v1 ^= v0; }
  TFR(13) TFR(15) TFR(26) TFR(6)   v0 += k1;  v1 += ks2 + 1u;
  TFR(17) TFR(29) TFR(16) TFR(24)  v0 += ks2; v1 += k0 + 2u;
  TFR(13) TFR(15) TFR(26) TFR(6)   v0 += k0;  v1 += k1 + 3u;
  TFR(17) TFR(29) TFR(16) TFR(24)  v0 += k1;  v1 += ks2 + 4u;
  TFR(13) TFR(15) TFR(26) TFR(6)   v0 += ks2; v1 += k0 + 5u;
#undef TFR
  y0 = v0; y1 = v1;
}

// Slot layout (u64 words), per (parity, batch): 16 slots x 4 words = 64 u64.
//  word0: [tag:13 | dist_bits:32 | inv_idx:19]   (reduce key)
//  word1..3: [x/y/z_bits:32 | tag:32]
// Every word carries the tag -> no ordering needed; a consistent snapshot is
// "all 64 words show tag i+1" (each word written exactly once per iteration).

#define PTS(F) F(0) F(1) F(2) F(3) F(4) F(5) F(6) F(7) \
               F(8) F(9) F(10) F(11) F(12) F(13) F(14) F(15)

__global__ __launch_bounds__(NTHR, 2)
void FPSampler_42099269435595_kernel(const float* __restrict__ xyz,
                                     const int* __restrict__ npoint_ptr,
                                     float* __restrict__ out,
                                     unsigned long long* __restrict__ slots,
                                     int N) {
#pragma clang fp contract(off)
  const int blk  = blockIdx.x;
  const int b    = blk >> 4;          // batch
  const int w    = blk & (WPB - 1);   // wg within batch
  const int tid  = threadIdx.x;
  const int wave = tid >> 6;
  const int lane = tid & 63;
  const int npoint = npoint_ptr[0];

  const float* __restrict__ xb = xyz + (size_t)b * N * 3;
  const int p0 = w * (N / WPB) + tid;

  // ---- point slice as NAMED SCALARS (pure SSA -> cannot be demoted to
  // scratch; R2's array+asm pin went to scratch, WRITE_SIZE 8->33MB) ----
#define DECL(k) float px##k, py##k, pz##k, dist##k;
  PTS(DECL)
#undef DECL
#define LOADK(k) { size_t p = (size_t)(p0 + k * NTHR); \
    px##k = xb[3*p+0]; py##k = xb[3*p+1]; pz##k = xb[3*p+2]; dist##k = 1e10f; }
  PTS(LOADK)
#undef LOADK
  // one-shot keep-alive: forces VGPR residency across the iteration loop
  asm volatile("" : "+v"(px0),"+v"(py0),"+v"(pz0),"+v"(px1),"+v"(py1),"+v"(pz1),
                    "+v"(px2),"+v"(py2),"+v"(pz2),"+v"(px3),"+v"(py3),"+v"(pz3));
  asm volatile("" : "+v"(px4),"+v"(py4),"+v"(pz4),"+v"(px5),"+v"(py5),"+v"(pz5),
                    "+v"(px6),"+v"(py6),"+v"(pz6),"+v"(px7),"+v"(py7),"+v"(pz7));
  asm volatile("" : "+v"(px8),"+v"(py8),"+v"(pz8),"+v"(px9),"+v"(py9),"+v"(pz9),
                    "+v"(px10),"+v"(py10),"+v"(pz10),"+v"(px11),"+v"(py11),"+v"(pz11));
  asm volatile("" : "+v"(px12),"+v"(py12),"+v"(pz12),"+v"(px13),"+v"(py13),"+v"(pz13),
                    "+v"(px14),"+v"(py14),"+v"(pz14),"+v"(px15),"+v"(py15),"+v"(pz15));

  // start = randint(fold_in(key(0),1),(16,),0,2^17)  (threefry, partitionable)
  uint32_t fk0, fk1, s0, s1, r0, r1;
  tf2x32(0u, 0u, 0u, 1u, fk0, fk1);          // fold_in(key(0), 1)
  tf2x32(fk0, fk1, 0u, 1u, s0, s1);          // split(key)[1]
  tf2x32(s0, s1, 0u, (uint32_t)b, r0, r1);   // random_bits element b
  uint32_t far = (r0 ^ r1) & 0x1FFFFu;       // % 131072 (span = 2^17)

  // initial centroid coords (uniform broadcast load, once)
  float cx = xb[3 * (size_t)far + 0];
  float cy = xb[3 * (size_t)far + 1];
  float cz = xb[3 * (size_t)far + 2];

  __shared__ unsigned long long lds_key[NWAVE];
  __shared__ float lds_x[NWAVE], lds_y[NWAVE], lds_z[NWAVE];
  __shared__ unsigned int lds_bfar;
  __shared__ float lds_bcx, lds_bcy, lds_bcz;

  float* out_xyz = out;                           // (B, npoint, 3)
  float* out_idx = out + (size_t)NB * npoint * 3; // (B, npoint) as float

  for (int i = 0; i < npoint; ++i) {
    // output writes from wave7 lane63 (NOT wave0 -> keeps publish path clean)
    if (w == 0 && tid == NTHR - 1) {
      size_t o = (size_t)b * npoint + i;
      out_xyz[3 * o + 0] = cx;
      out_xyz[3 * o + 1] = cy;
      out_xyz[3 * o + 2] = cz;
      out_idx[o] = (float)far;     // scan emits farthest BEFORE update
    }
    if (i == npoint - 1) break;

    // ---- distance update + per-thread argmax (register-resident) ----
    float best = -1.0f, bx = 0.f, by = 0.f, bz = 0.f;
    uint32_t bidx = 0;
#define UPD(k) { float dx = px##k - cx; float dy = py##k - cy; float dz = pz##k - cz; \
    float d = (dx * dx + dy * dy) + dz * dz; \
    float nd = fminf(dist##k, d); dist##k = nd; \
    if (nd > best) { best = nd; bidx = (uint32_t)(p0 + k * NTHR); \
                     bx = px##k; by = py##k; bz = pz##k; } }
    PTS(UPD)
#undef UPD

    // ---- per-wave reduce: key, then ballot+shfl the winner coords ----
    unsigned long long mykey =
        ((unsigned long long)__float_as_uint(best) << 19) |
        (unsigned long long)(0x7FFFFu - bidx);
    unsigned long long pk = mykey;
#pragma unroll
    for (int off = 32; off >= 1; off >>= 1) {
      unsigned long long o = __shfl_xor(pk, off);
      if (o > pk) pk = o;
    }
    unsigned long long bal = __ballot(mykey == pk);  // unique keys -> 1 bit
    int wl = __ffsll(bal) - 1;
    float wx = __shfl(bx, wl), wy = __shfl(by, wl), wz = __shfl(bz, wl);
    if (lane == 0) {
      lds_key[wave] = pk;
      lds_x[wave] = wx; lds_y[wave] = wy; lds_z[wave] = wz;
    }
    __syncthreads();

    unsigned long long* base =
        slots + (size_t)((i & 1) * NB + b) * (WPB * 4);
    const uint32_t tag = (uint32_t)(i + 1);

    if (wave == 0) {
      // cross-wave pick (lanes 0..7)
      unsigned long long k8 = (lane < NWAVE) ? lds_key[lane] : 0ull;
      unsigned long long m8 = k8;
#pragma unroll
      for (int off = 4; off >= 1; off >>= 1) {
        unsigned long long o = __shfl_xor(m8, off);
        if (o > m8) m8 = o;
      }
      unsigned long long bal8 = __ballot(lane < NWAVE && k8 == m8);
      int wv = __ffsll(bal8) - 1;

      // publish: lanes 0..3 store one tagged word each, in parallel
      unsigned long long wrd = 0;
      if (lane == 0) wrd = ((unsigned long long)tag << 51) | m8;
      if (lane == 1) wrd = ((unsigned long long)__float_as_uint(lds_x[wv]) << 32) | tag;
      if (lane == 2) wrd = ((unsigned long long)__float_as_uint(lds_y[wv]) << 32) | tag;
      if (lane == 3) wrd = ((unsigned long long)__float_as_uint(lds_z[wv]) << 32) | tag;
      if (lane < 4)
        __hip_atomic_store(base + w * 4 + lane, wrd, __ATOMIC_RELAXED,
                           __HIP_MEMORY_SCOPE_AGENT);

      // ---- depth-2 pipelined poll: check old value while next load flies ----
      unsigned long long v0 = __hip_atomic_load(base + lane, __ATOMIC_RELAXED,
                                                __HIP_MEMORY_SCOPE_AGENT);
      unsigned long long v1 = __hip_atomic_load(base + lane, __ATOMIC_RELAXED,
                                                __HIP_MEMORY_SCOPE_AGENT);
      for (;;) {
        uint32_t t = (lane & 3) ? (uint32_t)v0 : (uint32_t)(v0 >> 51);
        if (__all(t == tag)) break;
        v0 = v1;
        v1 = __hip_atomic_load(base + lane, __ATOMIC_RELAXED,
                               __HIP_MEMORY_SCOPE_AGENT);
      }
      unsigned long long v = v0;

      // redistribute: every lane grabs slot (lane&15)'s key, 16-way max
      unsigned long long key = __shfl(v, (lane & 15) << 2);
      unsigned long long gk = key;
#pragma unroll
      for (int off = 8; off >= 1; off >>= 1) {
        unsigned long long o = __shfl_xor(gk, off);
        if (o > gk) gk = o;
      }
      unsigned long long gbal = __ballot(key == gk);
      int ws = (__ffsll(gbal) - 1) & 15;   // winner slot
      uint32_t nfar = 0x7FFFFu - (uint32_t)(gk & 0x7FFFFu);
      float ncx = __uint_as_float((uint32_t)(__shfl(v, (ws << 2) | 1) >> 32));
      float ncy = __uint_as_float((uint32_t)(__shfl(v, (ws << 2) | 2) >> 32));
      float ncz = __uint_as_float((uint32_t)(__shfl(v, (ws << 2) | 3) >> 32));
      if (lane == 0) {
        lds_bfar = nfar;
        lds_bcx = ncx; lds_bcy = ncy; lds_bcz = ncz;
      }
    }
    __syncthreads();
    far = lds_bfar;
    cx = lds_bcx; cy = lds_bcy; cz = lds_bcz;
  }
}

extern "C" void kernel_launch(void* const* d_in, const int* in_sizes, int n_in,
                              void* d_out, int out_size, void* d_ws, size_t ws_size,
                              hipStream_t stream) {
  const float* xyz = (const float*)d_in[0];
  const int* npoint = (const int*)d_in[1];
  int N = in_sizes[0] / (NB * 3);  // 131072

  // zero slot words (2 parities x NB x WPB x 4 u64 = 16 KiB); tag 0 never
  // matches (tags start at 1), 0xAA poison decodes to tag != small i -> safe.
  hipMemsetAsync(d_ws, 0,
                 (size_t)2 * NB * WPB * 4 * sizeof(unsigned long long),
                 stream);
  FPSampler_42099269435595_kernel<<<NB * WPB, NTHR, 0, stream>>>(
      xyz, npoint, (float*)d_out, (unsigned long long*)d_ws, N);
}